// Round 14
// baseline (22.634 us; speedup 1.0000x reference)
//
#include <hip/hip_runtime.h>
#include <stdint.h>

#define NF   2344
#define ACCW 8
#define NA   38
#define TPB  512

__device__ __forceinline__ unsigned short f32_to_bf16(float f) {
    unsigned u = __float_as_uint(f);
    u += 0x7FFFu + ((u >> 16) & 1u);   // round-to-nearest-even
    return (unsigned short)(u >> 16);
}
__device__ __forceinline__ float bf16_lo(unsigned u) { return __uint_as_float(u << 16); }
__device__ __forceinline__ float bf16_hi(unsigned u) { return __uint_as_float(u & 0xFFFF0000u); }

// r11 structure (best: 22.0us, 32 waves/CU, per-color q-batch -> 19-gather
// burst) with WIDER per-pair index loads to cut TA line-events ~0.67x:
// lane h takes int4 @ 32j+16h (ints {8j+4h..+3}, j=0..3; pair covers 32B
// contiguous per instr) + three shared int2s for ints 32..37 (split .x/.y).
// 7 load instrs/color (vs 10), gathers stay 19/lane full-exec.
__global__ __launch_bounds__(TPB, 4) void nnue_fwd(
    const int* __restrict__ bfeat, const int* __restrict__ wfeat,
    const int* __restrict__ stm,
    const float* __restrict__ w1, const float* __restrict__ b1,
    const float* __restrict__ w2, const float* __restrict__ b2,
    float* __restrict__ out, int nbatch)
{
    __shared__ unsigned short tbl[NF * ACCW];   // bf16 table, 16B/row (37.5 KB)

    for (int j = threadIdx.x; j < (NF * ACCW) / 4; j += TPB) {
        float4 v = reinterpret_cast<const float4*>(w1)[j];
        unsigned lo = (unsigned)f32_to_bf16(v.x) | ((unsigned)f32_to_bf16(v.y) << 16);
        unsigned hi = (unsigned)f32_to_bf16(v.z) | ((unsigned)f32_to_bf16(v.w) << 16);
        reinterpret_cast<uint2*>(tbl)[j] = make_uint2(lo, hi);
    }
    __syncthreads();

    const int t = blockIdx.x * TPB + threadIdx.x;
    const int e = t >> 1;
    const int h = t & 1;
    if (e >= nbatch) return;

    const char* bb = reinterpret_cast<const char*>(bfeat + (long)e * NA);
    const char* wb = reinterpret_cast<const char*>(wfeat + (long)e * NA);

#define G(acc, idx) { \
        uint4 r = *reinterpret_cast<const uint4*>( \
            reinterpret_cast<const char*>(tbl) + ((unsigned)(idx) << 4)); \
        acc[0] += bf16_lo(r.x); acc[1] += bf16_hi(r.x); \
        acc[2] += bf16_lo(r.y); acc[3] += bf16_hi(r.y); \
        acc[4] += bf16_lo(r.z); acc[5] += bf16_hi(r.z); \
        acc[6] += bf16_lo(r.w); acc[7] += bf16_hi(r.w); }
#define G4(acc, v) { G(acc, v.x); G(acc, v.y); G(acc, v.z); G(acc, v.w); }

    float accB[8] = {0,0,0,0,0,0,0,0};
    float accW[8] = {0,0,0,0,0,0,0,0};
    int s;

    // ---- black phase (stm rides in the same load batch) ----
    {
        int4 q0 = *reinterpret_cast<const int4*>(bb +   0 + 16 * h);
        int4 q1 = *reinterpret_cast<const int4*>(bb +  32 + 16 * h);
        int4 q2 = *reinterpret_cast<const int4*>(bb +  64 + 16 * h);
        int4 q3 = *reinterpret_cast<const int4*>(bb +  96 + 16 * h);
        int2 t0 = *reinterpret_cast<const int2*>(bb + 128);   // ints 32,33
        int2 t1 = *reinterpret_cast<const int2*>(bb + 136);   // ints 34,35
        int2 t2 = *reinterpret_cast<const int2*>(bb + 144);   // ints 36,37
        s = stm[e];
        G4(accB, q0); G4(accB, q1); G4(accB, q2); G4(accB, q3);
        G(accB, h ? t0.y : t0.x);
        G(accB, h ? t2.x : t1.x);
        G(accB, h ? t2.y : t1.y);
    }

    asm volatile("" ::: "memory");   // keep the two phases' live sets separate

    // ---- white phase ----
    {
        int4 q0 = *reinterpret_cast<const int4*>(wb +   0 + 16 * h);
        int4 q1 = *reinterpret_cast<const int4*>(wb +  32 + 16 * h);
        int4 q2 = *reinterpret_cast<const int4*>(wb +  64 + 16 * h);
        int4 q3 = *reinterpret_cast<const int4*>(wb +  96 + 16 * h);
        int2 t0 = *reinterpret_cast<const int2*>(wb + 128);
        int2 t1 = *reinterpret_cast<const int2*>(wb + 136);
        int2 t2 = *reinterpret_cast<const int2*>(wb + 144);
        G4(accW, q0); G4(accW, q1); G4(accW, q2); G4(accW, q3);
        G(accW, h ? t0.y : t0.x);
        G(accW, h ? t2.x : t1.x);
        G(accW, h ? t2.y : t1.y);
    }
#undef G4
#undef G

    // ---- pair-combine (8 shfl): lane h finalizes color h (0=B, 1=W) ----
    float fin[8];
#pragma unroll
    for (int k = 0; k < 8; ++k) {
        float send = h ? accB[k] : accW[k];   // partial of the OTHER color
        float recv = __shfl_xor(send, 1);     // peer's partial of MY color
        fin[k] = (h ? accW[k] : accB[k]) + recv + b1[k];
    }

    float dlo = 0.f, dhi = 0.f;
#pragma unroll
    for (int k = 0; k < 8; ++k) {
        float v = fminf(fmaxf(fin[k], 0.f), 1.f);
        dlo += v * w2[k];
        dhi += v * w2[8 + k];
    }

    // stm==0 -> order [black, white]; color h sits at slot 0 iff (s==0)==(h==0).
    const float m = (((s == 0)) == (h == 0)) ? dlo : dhi;
    const float o = __shfl_xor(m, 1);
    if (h == 0) out[e] = m + o + b2[0];
}

extern "C" void kernel_launch(void* const* d_in, const int* in_sizes, int n_in,
                              void* d_out, int out_size, void* d_ws, size_t ws_size,
                              hipStream_t stream) {
    const int*   bfeat = (const int*)  d_in[0];
    const int*   wfeat = (const int*)  d_in[1];
    const int*   stm   = (const int*)  d_in[2];
    const float* w1    = (const float*)d_in[3];
    const float* b1    = (const float*)d_in[4];
    const float* w2    = (const float*)d_in[5];
    const float* b2    = (const float*)d_in[6];
    float* out = (float*)d_out;

    const int nbatch  = in_sizes[2];
    const long nthread = (long)nbatch * 2;
    const int grid = (int)((nthread + TPB - 1) / TPB);
    nnue_fwd<<<grid, TPB, 0, stream>>>(bfeat, wfeat, stm, w1, b1, w2, b2, out, nbatch);
}